// Round 1
// baseline (416.865 us; speedup 1.0000x reference)
//
#include <hip/hip_runtime.h>
#include <stdint.h>

// Problem constants (fixed by reference setup_inputs)
#define B_ROWS 4096
#define D_DIM  512
#define K_CODES 16384
#define EPS 1e-6f

typedef __attribute__((ext_vector_type(8))) short short8;   // 8 bf16 (raw bits)
typedef __attribute__((ext_vector_type(4))) float floatx4;  // MFMA accumulator

__device__ __forceinline__ unsigned short f2bf(float f) {
  // round-to-nearest-even fp32 -> bf16 (no NaN handling needed: inputs are finite)
  unsigned int u = __float_as_uint(f);
  u += 0x7FFFu + ((u >> 16) & 1u);
  return (unsigned short)(u >> 16);
}
__device__ __forceinline__ float bf2f(unsigned short h) {
  return __uint_as_float(((unsigned int)h) << 16);
}

__device__ __forceinline__ void load_lds16(const short* g, short* l) {
  // async global->LDS, 16B/lane; LDS dest = wave-uniform base + lane*16
  __builtin_amdgcn_global_load_lds(
      (const __attribute__((address_space(1))) void*)g,
      (__attribute__((address_space(3))) void*)l, 16, 0, 0);
}

// ---------------------------------------------------------------------------
// prep_x: x (4096x512 f32) -> A_cat (4096x1024 bf16: [x_hi | x_lo]) + row_term
// row_term[b] = sum(x^2) + 2*eps*sum(x) + D*eps^2
// ---------------------------------------------------------------------------
__global__ void prep_x_kernel(const float* __restrict__ x,
                              short* __restrict__ A,
                              float* __restrict__ row_term) {
  const int b = blockIdx.x;
  const int t = threadIdx.x;  // 64 threads = 1 wave
  const float* xr = x + (size_t)b * D_DIM;
  float4 v0 = ((const float4*)xr)[t * 2];
  float4 v1 = ((const float4*)xr)[t * 2 + 1];
  float vals[8] = {v0.x, v0.y, v0.z, v0.w, v1.x, v1.y, v1.z, v1.w};
  short8 hi, lo;
  float s = 0.f, q = 0.f;
#pragma unroll
  for (int i = 0; i < 8; ++i) {
    float v = vals[i];
    s += v;
    q += v * v;
    unsigned short h = f2bf(v);
    float r = v - bf2f(h);
    hi[i] = (short)h;
    lo[i] = (short)f2bf(r);
  }
  *(short8*)(A + (size_t)b * 1024 + t * 8) = hi;
  *(short8*)(A + (size_t)b * 1024 + 512 + t * 8) = lo;
#pragma unroll
  for (int m = 1; m < 64; m <<= 1) {
    s += __shfl_xor(s, m, 64);
    q += __shfl_xor(q, m, 64);
  }
  if (t == 0) row_term[b] = q + 2.0f * EPS * s + (float)D_DIM * EPS * EPS;
}

// ---------------------------------------------------------------------------
// prep_w: w (512x16384 f32, D-major) -> W_cat (16384x1024 bf16: [w_hi | w_lo],
// K-major i.e. transposed). LDS 64x64 tile transpose, conflict-free (+1 pad).
// ---------------------------------------------------------------------------
__global__ void prep_w_kernel(const float* __restrict__ w, short* __restrict__ W) {
  __shared__ float tile[64][65];
  const int k0 = blockIdx.x * 64;
  const int d0 = blockIdx.y * 64;
  const int tid = threadIdx.x;  // 256
#pragma unroll
  for (int i = 0; i < 16; ++i) {
    int idx = i * 256 + tid;
    int r = idx >> 6, c = idx & 63;  // r: d-local, c: k-local (coalesced read)
    tile[r][c] = w[(size_t)(d0 + r) * K_CODES + k0 + c];
  }
  __syncthreads();
#pragma unroll
  for (int i = 0; i < 16; ++i) {
    int idx = i * 256 + tid;
    int rk = idx >> 6, cd = idx & 63;  // rk: k-local, cd: d-local (coalesced write)
    float v = tile[cd][rk];
    unsigned short h = f2bf(v);
    float r = v - bf2f(h);
    W[(size_t)(k0 + rk) * 1024 + d0 + cd] = (short)h;
    W[(size_t)(k0 + rk) * 1024 + 512 + d0 + cd] = (short)f2bf(r);
  }
}

// ---------------------------------------------------------------------------
// prep_w_sums: col_term[k] = sum_d(w^2) - 2*eps*sum_d(w); also zeroes loss acc
// ---------------------------------------------------------------------------
__global__ void prep_w_sums_kernel(const float* __restrict__ w,
                                   float* __restrict__ col_term,
                                   float* __restrict__ loss_acc) {
  const int k = blockIdx.x * 256 + threadIdx.x;
  float s = 0.f, q = 0.f;
  for (int d = 0; d < D_DIM; ++d) {
    float v = w[(size_t)d * K_CODES + k];
    s += v;
    q += v * v;
  }
  col_term[k] = q - 2.0f * EPS * s;
  if (k == 0) loss_acc[0] = 0.0f;
}

// ---------------------------------------------------------------------------
// som_gemm: C[b,k] = x[b]·w[:,k] via 3-term hi/lo bf16 MFMA (virtual K = 1536)
// fused epilogue: d2 -> packed (d2_bits<<32)|k -> per-row min over the 128-col
// tile -> partial[nTile][row]. Tiles 128x128, BK=64, 4 waves, 16x16x32 MFMA.
// ---------------------------------------------------------------------------
__global__ __launch_bounds__(256) void som_gemm_kernel(
    const short* __restrict__ A, const short* __restrict__ W,
    const float* __restrict__ row_term, const float* __restrict__ col_term,
    unsigned long long* __restrict__ partial) {
  __shared__ __align__(16) short As[128 * 64];
  __shared__ __align__(16) short Bs[128 * 64];
  __shared__ unsigned long long lds_min[2][128];

  const int nt = blockIdx.x;  // 0..127
  const int mt = blockIdx.y;  // 0..31
  const int m0 = mt * 128, n0 = nt * 128;
  const int tid = threadIdx.x;
  const int wv = tid >> 6, lane = tid & 63;
  const int m_off = (wv & 1) * 64, n_off = (wv >> 1) * 64;
  const int q = lane >> 4, l15 = lane & 15;

  floatx4 acc[4][4];
  const floatx4 zero = {0.f, 0.f, 0.f, 0.f};
#pragma unroll
  for (int mi = 0; mi < 4; ++mi)
#pragma unroll
    for (int ni = 0; ni < 4; ++ni) acc[mi][ni] = zero;

  const int srow = lane >> 3;       // row within 8-row staging chunk
  const int scol = (lane & 7) * 8;  // col (8 bf16 = 16B)

  for (int kt = 0; kt < 24; ++kt) {
    // virtual k' in [0,1536): A cols = k'&1023  ([x_hi|x_lo], hi reused at k'>=1024)
    //                         W cols = k'<1024 ? k'&511 : k'-512  (hi,hi,lo)
    const int a_k0 = (kt * 64) & 1023;
    const int w_k0 = (kt < 16) ? ((kt * 64) & 511) : (kt * 64 - 512);
    __syncthreads();  // previous iter's ds_reads done before overwrite
#pragma unroll
    for (int i = 0; i < 4; ++i) {
      const int c = wv * 4 + i;  // chunk 0..15, covers rows c*8..c*8+7
      const int row = c * 8 + srow;
      load_lds16(A + (size_t)(m0 + row) * 1024 + a_k0 + scol, As + c * 512);
      load_lds16(W + (size_t)(n0 + row) * 1024 + w_k0 + scol, Bs + c * 512);
    }
    __syncthreads();  // waits vmcnt(0): staging complete
#pragma unroll
    for (int ks = 0; ks < 2; ++ks) {
      short8 af[4], bf[4];
#pragma unroll
      for (int mi = 0; mi < 4; ++mi)
        af[mi] = *(const short8*)(As + (m_off + mi * 16 + l15) * 64 + ks * 32 + q * 8);
#pragma unroll
      for (int ni = 0; ni < 4; ++ni)
        bf[ni] = *(const short8*)(Bs + (n_off + ni * 16 + l15) * 64 + ks * 32 + q * 8);
#pragma unroll
      for (int mi = 0; mi < 4; ++mi)
#pragma unroll
        for (int ni = 0; ni < 4; ++ni)
          acc[mi][ni] = __builtin_amdgcn_mfma_f32_16x16x32_bf16(
              af[mi], bf[ni], acc[mi][ni], 0, 0, 0);
    }
  }

  // epilogue: d2 = rt + ct - 2*cross; packed min (smallest d2, tie -> smallest k)
  float ct[4];
#pragma unroll
  for (int ni = 0; ni < 4; ++ni) ct[ni] = col_term[n0 + n_off + ni * 16 + l15];
  float rt[16];
#pragma unroll
  for (int mi = 0; mi < 4; ++mi)
#pragma unroll
    for (int r = 0; r < 4; ++r)
      rt[mi * 4 + r] = row_term[m0 + m_off + mi * 16 + q * 4 + r];

#pragma unroll
  for (int mi = 0; mi < 4; ++mi) {
#pragma unroll
    for (int r = 0; r < 4; ++r) {
      unsigned long long v = ~0ull;
#pragma unroll
      for (int ni = 0; ni < 4; ++ni) {
        float d2 = rt[mi * 4 + r] + ct[ni] - 2.0f * acc[mi][ni][r];
        d2 = fmaxf(d2, 0.0f);  // >=0 so float bit order == value order
        unsigned long long p =
            ((unsigned long long)__float_as_uint(d2) << 32) |
            (unsigned int)(n0 + n_off + ni * 16 + l15);
        v = p < v ? p : v;
      }
      // butterfly min across the 16 lanes sharing this C row
#pragma unroll
      for (int mms = 1; mms < 16; mms <<= 1) {
        unsigned long long o = __shfl_xor(v, mms, 64);
        v = o < v ? o : v;
      }
      if (l15 == 0) lds_min[wv >> 1][m_off + mi * 16 + q * 4 + r] = v;
    }
  }
  __syncthreads();
  if (tid < 128) {
    unsigned long long v0 = lds_min[0][tid];
    unsigned long long v1 = lds_min[1][tid];
    partial[(size_t)nt * B_ROWS + m0 + tid] = v1 < v0 ? v1 : v0;
  }
}

// ---------------------------------------------------------------------------
// finalize: per-row min over 128 N-tiles, sqrt, gather locations, loss partial
// ---------------------------------------------------------------------------
__global__ void finalize_kernel(const unsigned long long* __restrict__ partial,
                                const float* __restrict__ loc,
                                float* __restrict__ out,
                                float* __restrict__ loss_acc) {
  const int b = blockIdx.x * 256 + threadIdx.x;
  unsigned long long v = ~0ull;
  for (int nt = 0; nt < 128; ++nt) {
    unsigned long long p = partial[(size_t)nt * B_ROWS + b];
    v = p < v ? p : v;
  }
  unsigned int k = (unsigned int)(v & 0xFFFFFFFFu);
  float d2 = __uint_as_float((unsigned int)(v >> 32));
  float dist = sqrtf(d2);
  out[2 * b] = loc[2 * k];
  out[2 * b + 1] = loc[2 * k + 1];
  float s = dist;
#pragma unroll
  for (int m = 1; m < 64; m <<= 1) s += __shfl_xor(s, m, 64);
  __shared__ float wsum[4];
  const int wv = threadIdx.x >> 6, lane = threadIdx.x & 63;
  if (lane == 0) wsum[wv] = s;
  __syncthreads();
  if (threadIdx.x == 0) atomicAdd(loss_acc, wsum[0] + wsum[1] + wsum[2] + wsum[3]);
}

__global__ void write_loss_kernel(const float* __restrict__ loss_acc,
                                  float* __restrict__ out) {
  out[2 * B_ROWS] = loss_acc[0] * (1.0f / (float)B_ROWS);
}

// ---------------------------------------------------------------------------
// Workspace layout (bytes):
//   A_cat    4096*1024*2  =  8,388,608   @ 0
//   W_cat   16384*1024*2  = 33,554,432   @ 8,388,608
//   row_term  4096*4      =     16,384   @ 41,943,040
//   col_term 16384*4      =     65,536   @ 41,959,424
//   partial 128*4096*8    =  4,194,304   @ 42,024,960
//   loss_acc 4                           @ 46,219,264
// total ~46.2 MB
// ---------------------------------------------------------------------------
extern "C" void kernel_launch(void* const* d_in, const int* in_sizes, int n_in,
                              void* d_out, int out_size, void* d_ws, size_t ws_size,
                              hipStream_t stream) {
  const float* x = (const float*)d_in[0];
  const float* w = (const float*)d_in[1];
  const float* loc = (const float*)d_in[2];
  float* out = (float*)d_out;
  char* ws = (char*)d_ws;

  short* A = (short*)(ws + 0);
  short* W = (short*)(ws + 8388608);
  float* row_term = (float*)(ws + 41943040);
  float* col_term = (float*)(ws + 41959424);
  unsigned long long* partial = (unsigned long long*)(ws + 42024960);
  float* loss_acc = (float*)(ws + 46219264);

  prep_x_kernel<<<B_ROWS, 64, 0, stream>>>(x, A, row_term);
  prep_w_kernel<<<dim3(K_CODES / 64, D_DIM / 64), 256, 0, stream>>>(w, W);
  prep_w_sums_kernel<<<K_CODES / 256, 256, 0, stream>>>(w, col_term, loss_acc);
  som_gemm_kernel<<<dim3(K_CODES / 128, B_ROWS / 128), 256, 0, stream>>>(
      A, W, row_term, col_term, partial);
  finalize_kernel<<<B_ROWS / 256, 256, 0, stream>>>(partial, loc, out, loss_acc);
  write_loss_kernel<<<1, 1, 0, stream>>>(loss_acc, out);
}